// Round 1
// baseline (1161.871 us; speedup 1.0000x reference)
//
#include <hip/hip_runtime.h>

typedef float v2f __attribute__((ext_vector_type(2)));

#define NBATCH 131072
#define NSTEPS 499

__global__ __launch_bounds__(256, 2) void ode_euler_kernel(
    const float* __restrict__ y0,
    const float* __restrict__ t,
    const float* __restrict__ w1,
    const float* __restrict__ b1,
    const float* __restrict__ w2,
    const float* __restrict__ b2,
    float* __restrict__ out)
{
    // Per-pair weight layout (16 floats = 64 B per pair of hidden units):
    // [0..1]=S*w1[:,0] pair, [2..3]=S*w1[:,1] pair, [4..5]=S*b1 pair,
    // [6..7]=-2*w2[0,:] pair, [8..9]=-2*w2[1,:] pair, rest pad.
    __shared__ __align__(16) float Wf[25][16];
    __shared__ float dts[NSTEPS];
    __shared__ float cinit[2];

    const int tid = threadIdx.x;
    const float S = 2.8853900817779268f;  // 2*log2(e)

    if (tid < 50) {
        const int p = tid >> 1, s = tid & 1;
        Wf[p][0 + s] = S * w1[2 * tid + 0];
        Wf[p][2 + s] = S * w1[2 * tid + 1];
        Wf[p][4 + s] = S * b1[tid];
        Wf[p][6 + s] = -2.0f * w2[tid];
        Wf[p][8 + s] = -2.0f * w2[50 + tid];
    }
    if (tid == 0) {
        // tanh(a) = 1 - 2*r, so dy = (b2 + sum(w2)) + sum(-2*w2 * r)
        float s0 = b2[0], s1 = b2[1];
        for (int j = 0; j < 50; ++j) { s0 += w2[j]; s1 += w2[50 + j]; }
        cinit[0] = s0; cinit[1] = s1;
    }
    for (int k = tid; k < NSTEPS; k += 256) dts[k] = t[k + 1] - t[k];
    __syncthreads();

    const int i = blockIdx.x * 256 + tid;
    v2f y = ((const v2f*)y0)[i];
    v2f* outv = (v2f*)out;
    outv[i] = y;                       // out[0] = y0
    v2f* po = outv + NBATCH + i;       // out[k+1]

    const float c0 = cinit[0], c1 = cinit[1];

    for (int k = 0; k < NSTEPS; ++k) {
        asm volatile("" ::: "memory");  // force per-step LDS reloads (no 250-reg hoist)
        const float dt = dts[k];
        v2f a0 = {c0, 0.0f};
        v2f a1 = {c1, 0.0f};
        const v2f ysx = {y.x, y.x};
        const v2f ysy = {y.y, y.y};
        #pragma unroll
        for (int p = 0; p < 25; ++p) {
            const v2f* w = (const v2f*)&Wf[p][0];
            const v2f wx = w[0], wy = w[1], bs = w[2], m0 = w[3], m1 = w[4];
            // p = 2*log2e * (w1 . y + b1)  -> tanh via exp2
            v2f pv = wx * ysx + (wy * ysy + bs);
            pv.x = fminf(pv.x, 120.0f);  // overflow guard (tanh ~ 1 there anyway)
            pv.y = fminf(pv.y, 120.0f);
            v2f e;
            e.x = __builtin_amdgcn_exp2f(pv.x);
            e.y = __builtin_amdgcn_exp2f(pv.y);
            v2f d = e + 1.0f;
            // r = 1/d via bit-trick guess + 2 Newton iterations (VALU only)
            unsigned ux = 0x7EF311C3u - __float_as_uint(d.x);
            unsigned uy = 0x7EF311C3u - __float_as_uint(d.y);
            v2f r = {__uint_as_float(ux), __uint_as_float(uy)};
            r = r * (2.0f - d * r);
            r = r * (2.0f - d * r);
            a0 += m0 * r;
            a1 += m1 * r;
        }
        const float g0 = a0.x + a0.y;
        const float g1 = a1.x + a1.y;
        y.x = fmaf(dt, g0, y.x);
        y.y = fmaf(dt, g1, y.y);
        *po = y;
        po += NBATCH;
    }
}

extern "C" void kernel_launch(void* const* d_in, const int* in_sizes, int n_in,
                              void* d_out, int out_size, void* d_ws, size_t ws_size,
                              hipStream_t stream) {
    const float* y0 = (const float*)d_in[0];
    const float* t  = (const float*)d_in[1];
    const float* w1 = (const float*)d_in[2];
    const float* b1 = (const float*)d_in[3];
    const float* w2 = (const float*)d_in[4];
    const float* b2 = (const float*)d_in[5];
    float* out = (float*)d_out;
    ode_euler_kernel<<<NBATCH / 256, 256, 0, stream>>>(y0, t, w1, b1, w2, b2, out);
}

// Round 2
// 752.116 us; speedup vs baseline: 1.5448x; 1.5448x over previous
//
#include <hip/hip_runtime.h>

typedef float v2f __attribute__((ext_vector_type(2)));

#define NBATCH 131072
#define NSTEPS 499

template<int CTRL>
__device__ __forceinline__ float dppmov(float x) {
    int i = __builtin_amdgcn_mov_dpp(__float_as_int(x), CTRL, 0xF, 0xF, true);
    return __int_as_float(i);
}

__global__ __launch_bounds__(256, 4) void ode_euler_kernel(
    const float* __restrict__ y0,
    const float* __restrict__ t,
    const float* __restrict__ w1,
    const float* __restrict__ b1,
    const float* __restrict__ w2,
    const float* __restrict__ b2,
    float* __restrict__ out)
{
    __shared__ float dts[NSTEPS];
    const int tid = threadIdx.x;
    for (int k = tid; k < NSTEPS; k += 256) dts[k] = t[k + 1] - t[k];
    __syncthreads();

    const int gtid = blockIdx.x * 256 + tid;
    const int sub = gtid & 3;      // 4 lanes cooperate on one element
    const int e = gtid >> 2;       // element index

    // hidden-unit pair range: sub0 -> pairs 0..6 (7), sub1 -> 7..12, sub2 -> 13..18, sub3 -> 19..24
    const int start = (sub == 0) ? 0 : (1 + 6 * sub);
    const int count = (sub == 0) ? 7 : 6;

    const float S = 2.8853900817779268f;  // 2*log2(e):  tanh(a) = 1 - 2/(1 + 2^(S*a))

    // Weights in registers, folded: pv = S*(w1.y + b1); dy = c + sum(-2*w2 * rcp(1+2^pv))
    v2f wxv[7], wyv[7], bsv[7], m0v[7], m1v[7];
    #pragma unroll
    for (int q = 0; q < 7; ++q) {
        if (q < count) {
            const int p = start + q;
            const int u0 = 2 * p, u1 = 2 * p + 1;
            wxv[q] = (v2f){S * w1[2 * u0 + 0], S * w1[2 * u1 + 0]};
            wyv[q] = (v2f){S * w1[2 * u0 + 1], S * w1[2 * u1 + 1]};
            bsv[q] = (v2f){S * b1[u0], S * b1[u1]};
            m0v[q] = (v2f){-2.0f * w2[u0], -2.0f * w2[u1]};
            m1v[q] = (v2f){-2.0f * w2[50 + u0], -2.0f * w2[50 + u1]};
        } else {  // padded pair: pv=0 -> r=0.5, m=0 -> contributes 0
            wxv[q] = (v2f){0.f, 0.f}; wyv[q] = (v2f){0.f, 0.f}; bsv[q] = (v2f){0.f, 0.f};
            m0v[q] = (v2f){0.f, 0.f}; m1v[q] = (v2f){0.f, 0.f};
        }
    }
    // c = b2 + sum(w2) distributed: each thread carries w2-sum of ITS units (= -0.5*sum(m)),
    // b2 only on sub0; the per-step butterfly reduction completes the total.
    float cc0 = (sub == 0) ? b2[0] : 0.0f;
    float cc1 = (sub == 0) ? b2[1] : 0.0f;
    #pragma unroll
    for (int q = 0; q < 7; ++q) {
        cc0 -= 0.5f * (m0v[q].x + m0v[q].y);
        cc1 -= 0.5f * (m1v[q].x + m1v[q].y);
    }

    v2f y = ((const v2f*)y0)[e];
    v2f* outv = (v2f*)out;
    if (sub == 0) outv[e] = y;        // out[0] = y0
    v2f* po = outv + NBATCH + e;

    for (int k = 0; k < NSTEPS; ++k) {
        const float dt = dts[k];
        v2f a0 = {cc0, 0.0f};
        v2f a1 = {cc1, 0.0f};
        const v2f ysx = {y.x, y.x};
        const v2f ysy = {y.y, y.y};
        #pragma unroll
        for (int q = 0; q < 7; ++q) {
            v2f pv = wxv[q] * ysx + (wyv[q] * ysy + bsv[q]);
            v2f ev;
            ev.x = __builtin_amdgcn_exp2f(pv.x);
            ev.y = __builtin_amdgcn_exp2f(pv.y);
            v2f d = ev + 1.0f;                 // in [1, inf]; rcp(inf)=0 handles saturation
            v2f r;
            r.x = __builtin_amdgcn_rcpf(d.x);
            r.y = __builtin_amdgcn_rcpf(d.y);
            a0 += m0v[q] * r;
            a1 += m1v[q] * r;
        }
        // horizontal + butterfly across the 4 cooperating lanes (DPP quad_perm, pure VALU)
        v2f g = {a0.x + a0.y, a1.x + a1.y};
        v2f gs;
        gs.x = dppmov<0xB1>(g.x); gs.y = dppmov<0xB1>(g.y);  // xor 1
        g += gs;
        gs.x = dppmov<0x4E>(g.x); gs.y = dppmov<0x4E>(g.y);  // xor 2
        g += gs;
        const v2f dtv = {dt, dt};
        y += dtv * g;
        if (sub == 0) *po = y;
        po += NBATCH;
    }
}

extern "C" void kernel_launch(void* const* d_in, const int* in_sizes, int n_in,
                              void* d_out, int out_size, void* d_ws, size_t ws_size,
                              hipStream_t stream) {
    const float* y0 = (const float*)d_in[0];
    const float* t  = (const float*)d_in[1];
    const float* w1 = (const float*)d_in[2];
    const float* b1 = (const float*)d_in[3];
    const float* w2 = (const float*)d_in[4];
    const float* b2 = (const float*)d_in[5];
    float* out = (float*)d_out;
    ode_euler_kernel<<<(NBATCH * 4) / 256, 256, 0, stream>>>(y0, t, w1, b1, w2, b2, out);
}

// Round 3
// 743.546 us; speedup vs baseline: 1.5626x; 1.0115x over previous
//
#include <hip/hip_runtime.h>

typedef float v2f __attribute__((ext_vector_type(2)));

#define NBATCH 131072
#define NSTEPS 499

template<int CTRL>
__device__ __forceinline__ float dppmov(float x) {
    int i = __builtin_amdgcn_mov_dpp(__float_as_int(x), CTRL, 0xF, 0xF, true);
    return __int_as_float(i);
}

__global__ __launch_bounds__(256, 4) void ode_euler_kernel(
    const float* __restrict__ y0,
    const float* __restrict__ t,
    const float* __restrict__ w1,
    const float* __restrict__ b1,
    const float* __restrict__ w2,
    const float* __restrict__ b2,
    float* __restrict__ out)
{
    __shared__ float dts[NSTEPS];
    const int tid = threadIdx.x;
    for (int k = tid; k < NSTEPS; k += 256) dts[k] = t[k + 1] - t[k];
    __syncthreads();

    const int gtid = blockIdx.x * 256 + tid;
    const int sub = gtid & 3;      // 4 lanes cooperate on one element
    const int e = gtid >> 2;       // element index

    // hidden-unit pair range: sub0 -> pairs 0..6 (7), sub1 -> 7..12, sub2 -> 13..18, sub3 -> 19..24
    const int start = (sub == 0) ? 0 : (1 + 6 * sub);
    const int count = (sub == 0) ? 7 : 6;

    const float S = 2.8853900817779268f;  // 2*log2(e):  tanh(a) = 1 - 2/(1 + 2^(S*a))

    // Weights in registers, folded: pv = S*(w1.y + b1); dy = c + sum(-2*w2 * rcp(1+2^pv))
    v2f wxv[7], wyv[7], bsv[7], m0v[7], m1v[7];
    #pragma unroll
    for (int q = 0; q < 7; ++q) {
        if (q < count) {
            const int p = start + q;
            const int u0 = 2 * p, u1 = 2 * p + 1;
            wxv[q] = (v2f){S * w1[2 * u0 + 0], S * w1[2 * u1 + 0]};
            wyv[q] = (v2f){S * w1[2 * u0 + 1], S * w1[2 * u1 + 1]};
            bsv[q] = (v2f){S * b1[u0], S * b1[u1]};
            m0v[q] = (v2f){-2.0f * w2[u0], -2.0f * w2[u1]};
            m1v[q] = (v2f){-2.0f * w2[50 + u0], -2.0f * w2[50 + u1]};
        } else {  // padded pair: pv=0 -> r=0.5, m=0 -> contributes 0
            wxv[q] = (v2f){0.f, 0.f}; wyv[q] = (v2f){0.f, 0.f}; bsv[q] = (v2f){0.f, 0.f};
            m0v[q] = (v2f){0.f, 0.f}; m1v[q] = (v2f){0.f, 0.f};
        }
    }
    // c = b2 + sum(w2) distributed: each thread carries w2-sum of ITS units (= -0.5*sum(m)),
    // b2 only on sub0; the per-step butterfly reduction completes the total.
    float cc0 = (sub == 0) ? b2[0] : 0.0f;
    float cc1 = (sub == 0) ? b2[1] : 0.0f;
    #pragma unroll
    for (int q = 0; q < 7; ++q) {
        cc0 -= 0.5f * (m0v[q].x + m0v[q].y);
        cc1 -= 0.5f * (m1v[q].x + m1v[q].y);
    }

    // PIN weights into VGPRs: opaque asm output cannot be rematerialized, so the
    // compiler must keep these register-resident across the 499-step loop
    // (prevents the AGPR-copy / per-step-reload behavior seen at VGPR_Count=44).
    #pragma unroll
    for (int q = 0; q < 7; ++q) {
        asm volatile("" : "+v"(wxv[q]), "+v"(wyv[q]), "+v"(bsv[q]),
                          "+v"(m0v[q]), "+v"(m1v[q]));
    }
    asm volatile("" : "+v"(cc0), "+v"(cc1));

    v2f y = ((const v2f*)y0)[e];
    v2f* outv = (v2f*)out;
    if (sub == 0) __builtin_nontemporal_store(y, outv + e);   // out[0] = y0
    v2f* po = outv + NBATCH + e;

    for (int k = 0; k < NSTEPS; ++k) {
        const float dt = dts[k];
        v2f a0 = {cc0, 0.0f};
        v2f a1 = {cc1, 0.0f};
        const v2f ysx = {y.x, y.x};
        const v2f ysy = {y.y, y.y};
        #pragma unroll
        for (int q = 0; q < 7; ++q) {
            v2f pv = wxv[q] * ysx + (wyv[q] * ysy + bsv[q]);
            v2f ev;
            ev.x = __builtin_amdgcn_exp2f(pv.x);
            ev.y = __builtin_amdgcn_exp2f(pv.y);
            v2f d = ev + 1.0f;                 // in [1, inf]; rcp(inf)=0 handles saturation
            v2f r;
            r.x = __builtin_amdgcn_rcpf(d.x);
            r.y = __builtin_amdgcn_rcpf(d.y);
            a0 += m0v[q] * r;
            a1 += m1v[q] * r;
        }
        // horizontal + butterfly across the 4 cooperating lanes (DPP quad_perm, pure VALU)
        v2f g = {a0.x + a0.y, a1.x + a1.y};
        v2f gs;
        gs.x = dppmov<0xB1>(g.x); gs.y = dppmov<0xB1>(g.y);  // xor 1
        g += gs;
        gs.x = dppmov<0x4E>(g.x); gs.y = dppmov<0x4E>(g.y);  // xor 2
        g += gs;
        const v2f dtv = {dt, dt};
        y += dtv * g;
        if (sub == 0) __builtin_nontemporal_store(y, po);
        po += NBATCH;
    }
}

extern "C" void kernel_launch(void* const* d_in, const int* in_sizes, int n_in,
                              void* d_out, int out_size, void* d_ws, size_t ws_size,
                              hipStream_t stream) {
    const float* y0 = (const float*)d_in[0];
    const float* t  = (const float*)d_in[1];
    const float* w1 = (const float*)d_in[2];
    const float* b1 = (const float*)d_in[3];
    const float* w2 = (const float*)d_in[4];
    const float* b2 = (const float*)d_in[5];
    float* out = (float*)d_out;
    ode_euler_kernel<<<(NBATCH * 4) / 256, 256, 0, stream>>>(y0, t, w1, b1, w2, b2, out);
}